// Round 6
// baseline (816.147 us; speedup 1.0000x reference)
//
#include <hip/hip_runtime.h>
#include <stdint.h>

#define Nn 50000
#define Ne 800000

typedef __bf16 bf16x8 __attribute__((ext_vector_type(8)));
typedef float f32x4 __attribute__((ext_vector_type(4)));

// ---- ws layout (bytes) ----
#define H_OFF    0
#define AGG_OFF  (Nn * 128 * 4)                 // 25,600,000
#define FRAG_OFF (2 * Nn * 128 * 4)             // 51,200,000
// fragment segment offsets (bf16 elements, relative to FRAG_OFF)
#define EMBF   0
#define EW1F0  4096
#define EW2F0  36864
#define NW1F0  53248
#define NW2F0  86016
#define EW1F1  102400
#define EW2F1  135168
#define NW1F1  151552
#define NW2F1  184320
#define WOUTF  200704
#define FRAG_ELEMS 202752
#define W1C_OFF  (FRAG_OFF + FRAG_ELEMS * 2)    // 51,605,504
#define FLAG_OFF (W1C_OFF + 2 * 128 * 4)        // 51,606,528
// CSR build scratch
#define NSCAN    50176                          // 196 * 256 >= Nn
#define CUR_OFF  (FLAG_OFF + 16)                // 51,606,544
#define BS_OFF   (CUR_OFF + NSCAN * 4)          // 51,807,248
#define PERM_OFF (BS_OFF + 256 * 4)             // 51,808,272
#define HBF_OFF  (PERM_OFF + Ne * 4)            // 55,008,272 ; + 12.8MB = 67.8MB

static __device__ __forceinline__ unsigned short f2bf(float f) {
  union { float f; unsigned u; } v; v.f = f;
  unsigned r = v.u + 0x7fffu + ((v.u >> 16) & 1u);   // RNE
  return (unsigned short)(r >> 16);
}

static __device__ __forceinline__ float bf2f(unsigned short u) {
  union { unsigned u; float f; } t; t.u = ((unsigned)u) << 16; return t.f;
}

static __device__ __forceinline__ void st4bf(unsigned short* p, float4 v) {
  union { unsigned short u[4]; uint2 d; } t;
  t.u[0] = f2bf(v.x); t.u[1] = f2bf(v.y); t.u[2] = f2bf(v.z); t.u[3] = f2bf(v.w);
  *(uint2*)p = t.d;
}

static __device__ __forceinline__ f32x4 mfma16(bf16x8 a, bf16x8 b, f32x4 c) {
  return __builtin_amdgcn_mfma_f32_16x16x32_bf16(a, b, c, 0, 0, 0);
}

static __device__ __forceinline__ int eidx(const void* edges, int i, int is64) {
  if (is64) return (int)((const long long*)edges)[i];
  return ((const int*)edges)[i];
}

// ---------------- weight prep: f32 -> bf16 fragment-linear ----------------
__global__ __launch_bounds__(256) void prep_kernel(
    const float* __restrict__ w_in, const float* __restrict__ w_out,
    const float* __restrict__ edge_w1, const float* __restrict__ edge_w2,
    const float* __restrict__ node_w1, const float* __restrict__ node_w2,
    const void* __restrict__ edges,
    unsigned short* __restrict__ frags, float* __restrict__ w1c, int* __restrict__ flag) {
  int gid = blockIdx.x * 256 + threadIdx.x;
  if (gid == 0) {
    const unsigned* e32 = (const unsigned*)edges;
    int allz = 1;
    for (int i = 0; i < 64; ++i) if (e32[2 * i + 1] != 0u) { allz = 0; break; }
    *flag = allz;
  }
  if (gid < FRAG_ELEMS) {
    int base, KB, J10 = 0; const float* src;
    if      (gid < EW1F0) { base = EMBF;  KB = 1; src = w_in; }
    else if (gid < EW2F0) { base = EW1F0; KB = 8; src = edge_w1; }
    else if (gid < NW1F0) { base = EW2F0; KB = 4; src = edge_w2; }
    else if (gid < NW2F0) { base = NW1F0; KB = 8; src = node_w1; }
    else if (gid < EW1F1) { base = NW2F0; KB = 4; src = node_w2; }
    else if (gid < EW2F1) { base = EW1F1; KB = 8; src = edge_w1 + 257 * 128; }
    else if (gid < NW1F1) { base = EW2F1; KB = 4; src = edge_w2 + 128 * 128; }
    else if (gid < NW2F1) { base = NW1F1; KB = 8; src = node_w1 + 256 * 128; }
    else if (gid < WOUTF) { base = NW2F1; KB = 4; src = node_w2 + 128 * 128; }
    else                  { base = WOUTF; KB = 4; src = w_out; J10 = 1; }
    int f = gid - base;
    int i = f & 7, lane = (f >> 3) & 63;
    int rest = f >> 9;
    int kb = rest % KB, jt = rest / KB;
    int j = jt * 16 + (lane & 15);
    int k = kb * 32 + (lane >> 4) * 8 + i;
    float v;
    if (J10) v = (j < 10) ? src[k * 10 + j] : 0.f;
    else     v = src[k * 128 + j];
    frags[gid] = f2bf(v);
  } else if (gid < FRAG_ELEMS + 256) {
    int idx = gid - FRAG_ELEMS;
    int l = idx >> 7, j = idx & 127;
    w1c[idx] = edge_w1[l * (257 * 128) + 256 * 128 + j];
  }
}

// ---------------- CSR build: hist -> scan -> scatter ----------------
__global__ __launch_bounds__(256) void hist_kernel(
    const void* __restrict__ edges, const int* __restrict__ flag, int* __restrict__ cur) {
  int is64 = *flag;
  int i = blockIdx.x * 256 + threadIdx.x;
  if (i < Ne) atomicAdd(&cur[eidx(edges, i, is64)], 1);
}

__global__ __launch_bounds__(256) void scan1_kernel(int* __restrict__ cur, int* __restrict__ bsum) {
  __shared__ int s[256];
  int tid = threadIdx.x;
  int i = blockIdx.x * 256 + tid;
  s[tid] = cur[i];
  __syncthreads();
#pragma unroll
  for (int off = 1; off < 256; off <<= 1) {
    int t = (tid >= off) ? s[tid - off] : 0;
    __syncthreads();
    s[tid] += t;
    __syncthreads();
  }
  cur[i] = tid ? s[tid - 1] : 0;
  if (tid == 255) bsum[blockIdx.x] = s[255];
}

__global__ __launch_bounds__(256) void scan2_kernel(int* __restrict__ bsum) {
  __shared__ int s[256];
  int tid = threadIdx.x;
  s[tid] = bsum[tid];
  __syncthreads();
#pragma unroll
  for (int off = 1; off < 256; off <<= 1) {
    int t = (tid >= off) ? s[tid - off] : 0;
    __syncthreads();
    s[tid] += t;
    __syncthreads();
  }
  bsum[tid] = tid ? s[tid - 1] : 0;
}

__global__ __launch_bounds__(256) void scan3_kernel(int* __restrict__ cur, const int* __restrict__ bsum) {
  int i = blockIdx.x * 256 + threadIdx.x;
  cur[i] += bsum[blockIdx.x];
}

__global__ __launch_bounds__(256) void scatter_kernel(
    const void* __restrict__ edges, const int* __restrict__ flag,
    int* __restrict__ cur, int* __restrict__ perm) {
  int is64 = *flag;
  int i = blockIdx.x * 256 + threadIdx.x;
  if (i < Ne) {
    int r = eidx(edges, i, is64);
    int pos = atomicAdd(&cur[r], 1);
    perm[pos] = i;
  }
}

// ---------------- embedding: h = h0 @ w_in + b_in (writes f32 h + bf16 mirror) ----------------
__global__ __launch_bounds__(256) void embed_kernel(
    const float* __restrict__ h0, const float* __restrict__ b_in,
    const unsigned short* __restrict__ frags, float* __restrict__ h,
    unsigned short* __restrict__ hbf) {
  __shared__ __align__(16) unsigned short Xs[64 * 40];
  const int tid = threadIdx.x;
  const int n0 = blockIdx.x * 64;
  for (int f = tid; f < 512; f += 256) {
    int ns = f >> 3, c = (f & 7) * 4;
    int node = n0 + ns; if (node >= Nn) node = Nn - 1;
    st4bf(&Xs[ns * 40 + c], *(const float4*)&h0[(size_t)node * 32 + c]);
  }
  __syncthreads();
  const int lane = tid & 63, w = tid >> 6;
  const int s = lane & 15, q = lane >> 4;
  const int jt0 = 2 * w;
  f32x4 z = {0.f, 0.f, 0.f, 0.f};
  f32x4 acc[2][4];
#pragma unroll
  for (int n = 0; n < 2; ++n)
#pragma unroll
    for (int e = 0; e < 4; ++e) acc[n][e] = z;
  const unsigned short* Af = frags + EMBF;
  bf16x8 a0 = *(const bf16x8*)(Af + ((jt0 + 0) * 64 + lane) * 8);
  bf16x8 a1 = *(const bf16x8*)(Af + ((jt0 + 1) * 64 + lane) * 8);
#pragma unroll
  for (int et = 0; et < 4; ++et) {
    bf16x8 b = *(const bf16x8*)&Xs[(16 * et + s) * 40 + q * 8];
    acc[0][et] = mfma16(a0, b, acc[0][et]);
    acc[1][et] = mfma16(a1, b, acc[1][et]);
  }
#pragma unroll
  for (int n = 0; n < 2; ++n) {
    int j0 = (jt0 + n) * 16 + 4 * q;
    float4 bi = *(const float4*)&b_in[j0];
#pragma unroll
    for (int et = 0; et < 4; ++et) {
      int node = n0 + 16 * et + s;
      if (node < Nn) {
        float4 o;
        o.x = acc[n][et][0] + bi.x; o.y = acc[n][et][1] + bi.y;
        o.z = acc[n][et][2] + bi.z; o.w = acc[n][et][3] + bi.w;
        *(float4*)&h[(size_t)node * 128 + j0] = o;
        st4bf(&hbf[(size_t)node * 128 + j0], o);
      }
    }
  }
}

// ---------------- edge MLP: ONE WAVE = 64 edges, all 128 output channels ----------------
// Gathers issued once per edge (no cross-wave redundancy). Sorted rows ->
// interior runs stored directly (exclusive ownership), boundary runs atomic.
__global__ __launch_bounds__(64, 2) void edge_kernel(
    const unsigned short* __restrict__ hbf, const void* __restrict__ edges,
    const float* __restrict__ distances, const float* __restrict__ edge_mask,
    const float* __restrict__ eb1, const float* __restrict__ eb2,
    const unsigned short* __restrict__ w1f, const unsigned short* __restrict__ w2f,
    const float* __restrict__ w1c, float* __restrict__ agg,
    const int* __restrict__ flag, const int* __restrict__ perm) {
  __shared__ __align__(16) unsigned short U[64 * 136];   // T1 (bf16) then Outb (bf16)
  __shared__ float dist_s[64], em_s[64];
  __shared__ int row_s[64], col_s[64];
  const int tid = threadIdx.x;               // 0..63, one wave
  const int e0 = blockIdx.x * 64;
  const int is64 = *flag;
  {
    int eid = perm[e0 + tid];
    row_s[tid]  = eidx(edges, eid, is64);
    col_s[tid]  = eidx(edges, Ne + eid, is64);
    dist_s[tid] = distances[eid];
    em_s[tid]   = edge_mask[eid];
  }
  __syncthreads();   // single wave: compiles to waitcnt (+barrier), cheap
  const int s = tid & 15, q = tid >> 4;
  // per-lane node pointers for the 4 edge sub-tiles
  const unsigned short* bp[2][4];
#pragma unroll
  for (int et = 0; et < 4; ++et) {
    bp[0][et] = hbf + (size_t)row_s[16 * et + s] * 128 + q * 8;
    bp[1][et] = hbf + (size_t)col_s[16 * et + s] * 128 + q * 8;
  }
  f32x4 z = {0.f, 0.f, 0.f, 0.f};
  f32x4 acc[8][4];
#pragma unroll
  for (int jt = 0; jt < 8; ++jt)
#pragma unroll
    for (int e = 0; e < 4; ++e) acc[jt][e] = z;
  // GEMM1: K=256 ([h_row | h_col]); B gathered once, reused across all 8 jt
#pragma unroll
  for (int kb = 0; kb < 8; ++kb) {
    bf16x8 b[4];
#pragma unroll
    for (int et = 0; et < 4; ++et)
      b[et] = *(const bf16x8*)(bp[kb >> 2][et] + (kb & 3) * 32);
#pragma unroll
    for (int jt = 0; jt < 8; ++jt) {
      bf16x8 a = *(const bf16x8*)(w1f + ((jt * 8 + kb) * 64 + tid) * 8);
#pragma unroll
      for (int et = 0; et < 4; ++et)
        acc[jt][et] = mfma16(a, b[et], acc[jt][et]);
    }
  }
  // epilogue 1: + dist*w1c + b1, relu -> T1 (bf16)
  unsigned short* T1s = U;
  {
    float de[4];
#pragma unroll
    for (int et = 0; et < 4; ++et) de[et] = dist_s[16 * et + s];
#pragma unroll
    for (int jt = 0; jt < 8; ++jt) {
      int j0 = jt * 16 + 4 * q;
      float4 wc = *(const float4*)&w1c[j0];
      float4 bb = *(const float4*)&eb1[j0];
#pragma unroll
      for (int et = 0; et < 4; ++et) {
        float r0 = fmaxf(acc[jt][et][0] + de[et] * wc.x + bb.x, 0.f);
        float r1 = fmaxf(acc[jt][et][1] + de[et] * wc.y + bb.y, 0.f);
        float r2 = fmaxf(acc[jt][et][2] + de[et] * wc.z + bb.z, 0.f);
        float r3 = fmaxf(acc[jt][et][3] + de[et] * wc.w + bb.w, 0.f);
        union { unsigned short u[4]; uint2 d; } t;
        t.u[0] = f2bf(r0); t.u[1] = f2bf(r1); t.u[2] = f2bf(r2); t.u[3] = f2bf(r3);
        *(uint2*)&T1s[(16 * et + s) * 136 + j0] = t.d;
      }
    }
  }
  __syncthreads();
  // GEMM2: K=128
  f32x4 acc2[8][4];
#pragma unroll
  for (int jt = 0; jt < 8; ++jt)
#pragma unroll
    for (int e = 0; e < 4; ++e) acc2[jt][e] = z;
#pragma unroll
  for (int kb = 0; kb < 4; ++kb) {
    bf16x8 b[4];
#pragma unroll
    for (int et = 0; et < 4; ++et)
      b[et] = *(const bf16x8*)&T1s[(16 * et + s) * 136 + kb * 32 + q * 8];
#pragma unroll
    for (int jt = 0; jt < 8; ++jt) {
      bf16x8 a = *(const bf16x8*)(w2f + ((jt * 4 + kb) * 64 + tid) * 8);
#pragma unroll
      for (int et = 0; et < 4; ++et)
        acc2[jt][et] = mfma16(a, b[et], acc2[jt][et]);
    }
  }
  __syncthreads();   // T1 dead; Outb aliases it
  // epilogue 2: + b2, relu, * edge_mask -> Outb (bf16)
  unsigned short* Outb = U;
#pragma unroll
  for (int jt = 0; jt < 8; ++jt) {
    int j0 = jt * 16 + 4 * q;
    float4 bb = *(const float4*)&eb2[j0];
#pragma unroll
    for (int et = 0; et < 4; ++et) {
      int ee = 16 * et + s;
      float em = em_s[ee];
      float4 o;
      o.x = fmaxf(acc2[jt][et][0] + bb.x, 0.f) * em;
      o.y = fmaxf(acc2[jt][et][1] + bb.y, 0.f) * em;
      o.z = fmaxf(acc2[jt][et][2] + bb.z, 0.f) * em;
      o.w = fmaxf(acc2[jt][et][3] + bb.w, 0.f) * em;
      st4bf(&Outb[ee * 136 + j0], o);
    }
  }
  __syncthreads();
  // run-length reduce over sorted rows: lane owns channel pair (2t, 2t+1).
  // Interior rows (not first/last of block) are exclusively owned -> plain store.
  const int rowFirst = row_s[0], rowLast = row_s[63];
  float s0 = 0.f, s1 = 0.f;
  int prow = rowFirst;
  for (int es = 0; es < 64; ++es) {
    int r = row_s[es];
    if (r != prow) {
      float* ap = &agg[(size_t)prow * 128 + 2 * tid];
      if (prow == rowFirst || prow == rowLast) {
        atomicAdd(ap + 0, s0); atomicAdd(ap + 1, s1);
      } else {
        *(float2*)ap = make_float2(s0, s1);
      }
      s0 = 0.f; s1 = 0.f; prow = r;
    }
    unsigned pv = *(const unsigned*)&Outb[es * 136 + 2 * tid];
    s0 += bf2f((unsigned short)(pv & 0xffffu));
    s1 += bf2f((unsigned short)(pv >> 16));
  }
  {
    float* ap = &agg[(size_t)prow * 128 + 2 * tid];
    atomicAdd(ap + 0, s0); atomicAdd(ap + 1, s1);   // last run always boundary
  }
}

// ---------------- node MLP: h = (h + MLP([h,agg])) * node_mask ----------------
__global__ __launch_bounds__(256, 8) void node_kernel(
    float* __restrict__ h, unsigned short* __restrict__ hbf,
    const float* __restrict__ agg, const float* __restrict__ node_mask,
    const float* __restrict__ nb1, const float* __restrict__ nb2,
    const unsigned short* __restrict__ w1f, const unsigned short* __restrict__ w2f) {
  __shared__ __align__(16) unsigned short U[64 * 136];   // Ms then T1s (aliased)
  const int tid = threadIdx.x;
  const int n0 = blockIdx.x * 64;
  const int cg = (tid & 31) * 4;
  for (int ns = tid >> 5; ns < 64; ns += 8) {
    int node = n0 + ns; if (node >= Nn) node = Nn - 1;
    st4bf(&U[ns * 136 + cg], *(const float4*)&agg[(size_t)node * 128 + cg]);
  }
  __syncthreads();
  const int lane = tid & 63, w = tid >> 6;
  const int s = lane & 15, q = lane >> 4;
  const int jt0 = 2 * w;
  const unsigned short* bp[4];
#pragma unroll
  for (int et = 0; et < 4; ++et) {
    int node = n0 + 16 * et + s; if (node >= Nn) node = Nn - 1;
    bp[et] = hbf + (size_t)node * 128 + q * 8;
  }
  f32x4 z = {0.f, 0.f, 0.f, 0.f};
  f32x4 acc[2][4];
#pragma unroll
  for (int n = 0; n < 2; ++n)
#pragma unroll
    for (int e = 0; e < 4; ++e) acc[n][e] = z;
#pragma unroll
  for (int kb = 0; kb < 8; ++kb) {
    bf16x8 a0 = *(const bf16x8*)(w1f + (((jt0 + 0) * 8 + kb) * 64 + lane) * 8);
    bf16x8 a1 = *(const bf16x8*)(w1f + (((jt0 + 1) * 8 + kb) * 64 + lane) * 8);
#pragma unroll
    for (int et = 0; et < 4; ++et) {
      bf16x8 b;
      if (kb < 4) b = *(const bf16x8*)(bp[et] + kb * 32);
      else        b = *(const bf16x8*)&U[(16 * et + s) * 136 + (kb & 3) * 32 + q * 8];
      acc[0][et] = mfma16(a0, b, acc[0][et]);
      acc[1][et] = mfma16(a1, b, acc[1][et]);
    }
  }
  __syncthreads();   // Ms dead; T1s aliases it
#pragma unroll
  for (int n = 0; n < 2; ++n) {
    int j0 = (jt0 + n) * 16 + 4 * q;
    float4 bb = *(const float4*)&nb1[j0];
#pragma unroll
    for (int et = 0; et < 4; ++et) {
      float r0 = fmaxf(acc[n][et][0] + bb.x, 0.f);
      float r1 = fmaxf(acc[n][et][1] + bb.y, 0.f);
      float r2 = fmaxf(acc[n][et][2] + bb.z, 0.f);
      float r3 = fmaxf(acc[n][et][3] + bb.w, 0.f);
      union { unsigned short u[4]; uint2 d; } t;
      t.u[0] = f2bf(r0); t.u[1] = f2bf(r1); t.u[2] = f2bf(r2); t.u[3] = f2bf(r3);
      *(uint2*)&U[(16 * et + s) * 136 + j0] = t.d;
    }
  }
  __syncthreads();
  f32x4 acc2[2][4];
#pragma unroll
  for (int n = 0; n < 2; ++n)
#pragma unroll
    for (int e = 0; e < 4; ++e) acc2[n][e] = z;
#pragma unroll
  for (int kb = 0; kb < 4; ++kb) {
    bf16x8 a0 = *(const bf16x8*)(w2f + (((jt0 + 0) * 4 + kb) * 64 + lane) * 8);
    bf16x8 a1 = *(const bf16x8*)(w2f + (((jt0 + 1) * 4 + kb) * 64 + lane) * 8);
#pragma unroll
    for (int et = 0; et < 4; ++et) {
      bf16x8 b = *(const bf16x8*)&U[(16 * et + s) * 136 + kb * 32 + q * 8];
      acc2[0][et] = mfma16(a0, b, acc2[0][et]);
      acc2[1][et] = mfma16(a1, b, acc2[1][et]);
    }
  }
#pragma unroll
  for (int n = 0; n < 2; ++n) {
    int j0 = (jt0 + n) * 16 + 4 * q;
    float4 bb = *(const float4*)&nb2[j0];
#pragma unroll
    for (int et = 0; et < 4; ++et) {
      int node = n0 + 16 * et + s;
      if (node < Nn) {
        float nm = node_mask[node];
        float4 old = *(const float4*)&h[(size_t)node * 128 + j0];
        float4 o;
        o.x = (old.x + acc2[n][et][0] + bb.x) * nm;
        o.y = (old.y + acc2[n][et][1] + bb.y) * nm;
        o.z = (old.z + acc2[n][et][2] + bb.z) * nm;
        o.w = (old.w + acc2[n][et][3] + bb.w) * nm;
        *(float4*)&h[(size_t)node * 128 + j0] = o;
        st4bf(&hbf[(size_t)node * 128 + j0], o);
      }
    }
  }
}

// ---------------- output projection: out = h @ w_out + b_out (direct-global B) ----------------
__global__ __launch_bounds__(256) void out_kernel(
    const unsigned short* __restrict__ hbf, const float* __restrict__ b_out,
    const unsigned short* __restrict__ wf, float* __restrict__ out) {
  const int tid = threadIdx.x;
  const int n0 = blockIdx.x * 64;
  const int lane = tid & 63, w = tid >> 6;
  const int s = lane & 15, q = lane >> 4;
  int node = n0 + 16 * w + s;
  int nc = (node < Nn) ? node : (Nn - 1);
  f32x4 acc = {0.f, 0.f, 0.f, 0.f};
#pragma unroll
  for (int kb = 0; kb < 4; ++kb) {
    bf16x8 a = *(const bf16x8*)(wf + (kb * 64 + lane) * 8);
    bf16x8 b = *(const bf16x8*)(hbf + (size_t)nc * 128 + kb * 32 + q * 8);
    acc = mfma16(a, b, acc);
  }
  if (node < Nn) {
#pragma unroll
    for (int r = 0; r < 4; ++r) {
      int j = 4 * q + r;
      if (j < 10) out[(size_t)node * 10 + j] = acc[r] + b_out[j];
    }
  }
}

extern "C" void kernel_launch(void* const* d_in, const int* in_sizes, int n_in,
                              void* d_out, int out_size, void* d_ws, size_t ws_size,
                              hipStream_t stream) {
  const float* h0        = (const float*)d_in[0];
  const void*  edges     = d_in[1];
  const float* dist      = (const float*)d_in[2];
  const float* node_mask = (const float*)d_in[3];
  const float* edge_mask = (const float*)d_in[4];
  const float* w_in      = (const float*)d_in[5];
  const float* b_in      = (const float*)d_in[6];
  const float* w_out     = (const float*)d_in[7];
  const float* b_out     = (const float*)d_in[8];
  const float* edge_w1   = (const float*)d_in[9];
  const float* edge_b1   = (const float*)d_in[10];
  const float* edge_w2   = (const float*)d_in[11];
  const float* edge_b2   = (const float*)d_in[12];
  const float* node_w1   = (const float*)d_in[13];
  const float* node_b1   = (const float*)d_in[14];
  const float* node_w2   = (const float*)d_in[15];
  const float* node_b2   = (const float*)d_in[16];

  char* ws = (char*)d_ws;
  float* h               = (float*)(ws + H_OFF);
  float* agg             = (float*)(ws + AGG_OFF);
  unsigned short* frags  = (unsigned short*)(ws + FRAG_OFF);
  float* w1c             = (float*)(ws + W1C_OFF);
  int* flag              = (int*)(ws + FLAG_OFF);
  int* cur               = (int*)(ws + CUR_OFF);
  int* bsum              = (int*)(ws + BS_OFF);
  int* perm              = (int*)(ws + PERM_OFF);
  unsigned short* hbf    = (unsigned short*)(ws + HBF_OFF);

  hipMemsetAsync(cur, 0, (NSCAN + 256) * 4, stream);
  prep_kernel<<<793, 256, 0, stream>>>(w_in, w_out, edge_w1, edge_w2,
                                       node_w1, node_w2, edges, frags, w1c, flag);
  hist_kernel<<<(Ne + 255) / 256, 256, 0, stream>>>(edges, flag, cur);
  scan1_kernel<<<NSCAN / 256, 256, 0, stream>>>(cur, bsum);
  scan2_kernel<<<1, 256, 0, stream>>>(bsum);
  scan3_kernel<<<NSCAN / 256, 256, 0, stream>>>(cur, bsum);
  scatter_kernel<<<(Ne + 255) / 256, 256, 0, stream>>>(edges, flag, cur, perm);

  const int nb_n = (Nn + 63) / 64;  // 782
  embed_kernel<<<nb_n, 256, 0, stream>>>(h0, b_in, frags, h, hbf);
  for (int l = 0; l < 2; ++l) {
    hipMemsetAsync(agg, 0, (size_t)Nn * 128 * 4, stream);
    edge_kernel<<<Ne / 64, 64, 0, stream>>>(
        hbf, edges, dist, edge_mask,
        edge_b1 + l * 128, edge_b2 + l * 128,
        frags + (l ? EW1F1 : EW1F0), frags + (l ? EW2F1 : EW2F0),
        w1c + l * 128, agg, flag, perm);
    node_kernel<<<nb_n, 256, 0, stream>>>(
        h, hbf, agg, node_mask,
        node_b1 + l * 128, node_b2 + l * 128,
        frags + (l ? NW1F1 : NW1F0), frags + (l ? NW2F1 : NW2F0));
  }
  out_kernel<<<nb_n, 256, 0, stream>>>(hbf, b_out, frags + WOUTF, (float*)d_out);
}

// Round 7
// 778.504 us; speedup vs baseline: 1.0484x; 1.0484x over previous
//
#include <hip/hip_runtime.h>
#include <stdint.h>

#define Nn 50000
#define Ne 800000

typedef __bf16 bf16x8 __attribute__((ext_vector_type(8)));
typedef float f32x4 __attribute__((ext_vector_type(4)));

// ---- ws layout (bytes) ----
#define H_OFF    0
#define AGG_OFF  (Nn * 128 * 4)                 // 25,600,000
#define FRAG_OFF (2 * Nn * 128 * 4)             // 51,200,000
// fragment segment offsets (bf16 elements, relative to FRAG_OFF)
#define EMBF   0
#define EW1F0  4096
#define EW2F0  36864
#define NW1F0  53248
#define NW2F0  86016
#define EW1F1  102400
#define EW2F1  135168
#define NW1F1  151552
#define NW2F1  184320
#define WOUTF  200704
#define FRAG_ELEMS 202752
#define W1C_OFF  (FRAG_OFF + FRAG_ELEMS * 2)    // 51,605,504
#define FLAG_OFF (W1C_OFF + 2 * 128 * 4)        // 51,606,528
// CSR build scratch
#define NSCAN    50176                          // 196 * 256 >= Nn
#define CUR_OFF  (FLAG_OFF + 16)                // 51,606,544
#define BS_OFF   (CUR_OFF + NSCAN * 4)          // 51,807,248
#define PERM_OFF (BS_OFF + 256 * 4)             // 51,808,272
#define HBF_OFF  (PERM_OFF + Ne * 4)            // 55,008,272 ; + 12.8MB = 67.8MB

static __device__ __forceinline__ unsigned short f2bf(float f) {
  union { float f; unsigned u; } v; v.f = f;
  unsigned r = v.u + 0x7fffu + ((v.u >> 16) & 1u);   // RNE
  return (unsigned short)(r >> 16);
}

static __device__ __forceinline__ float bf2f(unsigned short u) {
  union { unsigned u; float f; } t; t.u = ((unsigned)u) << 16; return t.f;
}

static __device__ __forceinline__ void st4bf(unsigned short* p, float4 v) {
  union { unsigned short u[4]; uint2 d; } t;
  t.u[0] = f2bf(v.x); t.u[1] = f2bf(v.y); t.u[2] = f2bf(v.z); t.u[3] = f2bf(v.w);
  *(uint2*)p = t.d;
}

static __device__ __forceinline__ f32x4 mfma16(bf16x8 a, bf16x8 b, f32x4 c) {
  return __builtin_amdgcn_mfma_f32_16x16x32_bf16(a, b, c, 0, 0, 0);
}

static __device__ __forceinline__ int eidx(const void* edges, int i, int is64) {
  if (is64) return (int)((const long long*)edges)[i];
  return ((const int*)edges)[i];
}

// ---------------- weight prep: f32 -> bf16 fragment-linear ----------------
__global__ __launch_bounds__(256) void prep_kernel(
    const float* __restrict__ w_in, const float* __restrict__ w_out,
    const float* __restrict__ edge_w1, const float* __restrict__ edge_w2,
    const float* __restrict__ node_w1, const float* __restrict__ node_w2,
    const void* __restrict__ edges,
    unsigned short* __restrict__ frags, float* __restrict__ w1c, int* __restrict__ flag) {
  int gid = blockIdx.x * 256 + threadIdx.x;
  if (gid == 0) {
    const unsigned* e32 = (const unsigned*)edges;
    int allz = 1;
    for (int i = 0; i < 64; ++i) if (e32[2 * i + 1] != 0u) { allz = 0; break; }
    *flag = allz;
  }
  if (gid < FRAG_ELEMS) {
    int base, KB, J10 = 0; const float* src;
    if      (gid < EW1F0) { base = EMBF;  KB = 1; src = w_in; }
    else if (gid < EW2F0) { base = EW1F0; KB = 8; src = edge_w1; }
    else if (gid < NW1F0) { base = EW2F0; KB = 4; src = edge_w2; }
    else if (gid < NW2F0) { base = NW1F0; KB = 8; src = node_w1; }
    else if (gid < EW1F1) { base = NW2F0; KB = 4; src = node_w2; }
    else if (gid < EW2F1) { base = EW1F1; KB = 8; src = edge_w1 + 257 * 128; }
    else if (gid < NW1F1) { base = EW2F1; KB = 4; src = edge_w2 + 128 * 128; }
    else if (gid < NW2F1) { base = NW1F1; KB = 8; src = node_w1 + 256 * 128; }
    else if (gid < WOUTF) { base = NW2F1; KB = 4; src = node_w2 + 128 * 128; }
    else                  { base = WOUTF; KB = 4; src = w_out; J10 = 1; }
    int f = gid - base;
    int i = f & 7, lane = (f >> 3) & 63;
    int rest = f >> 9;
    int kb = rest % KB, jt = rest / KB;
    int j = jt * 16 + (lane & 15);
    int k = kb * 32 + (lane >> 4) * 8 + i;
    float v;
    if (J10) v = (j < 10) ? src[k * 10 + j] : 0.f;
    else     v = src[k * 128 + j];
    frags[gid] = f2bf(v);
  } else if (gid < FRAG_ELEMS + 256) {
    int idx = gid - FRAG_ELEMS;
    int l = idx >> 7, j = idx & 127;
    w1c[idx] = edge_w1[l * (257 * 128) + 256 * 128 + j];
  }
}

// ---------------- CSR build: hist -> scan -> scatter ----------------
__global__ __launch_bounds__(256) void hist_kernel(
    const void* __restrict__ edges, const int* __restrict__ flag, int* __restrict__ cur) {
  int is64 = *flag;
  int i = blockIdx.x * 256 + threadIdx.x;
  if (i < Ne) atomicAdd(&cur[eidx(edges, i, is64)], 1);
}

__global__ __launch_bounds__(256) void scan1_kernel(int* __restrict__ cur, int* __restrict__ bsum) {
  __shared__ int s[256];
  int tid = threadIdx.x;
  int i = blockIdx.x * 256 + tid;
  s[tid] = cur[i];
  __syncthreads();
#pragma unroll
  for (int off = 1; off < 256; off <<= 1) {
    int t = (tid >= off) ? s[tid - off] : 0;
    __syncthreads();
    s[tid] += t;
    __syncthreads();
  }
  cur[i] = tid ? s[tid - 1] : 0;
  if (tid == 255) bsum[blockIdx.x] = s[255];
}

__global__ __launch_bounds__(256) void scan2_kernel(int* __restrict__ bsum) {
  __shared__ int s[256];
  int tid = threadIdx.x;
  s[tid] = bsum[tid];
  __syncthreads();
#pragma unroll
  for (int off = 1; off < 256; off <<= 1) {
    int t = (tid >= off) ? s[tid - off] : 0;
    __syncthreads();
    s[tid] += t;
    __syncthreads();
  }
  bsum[tid] = tid ? s[tid - 1] : 0;
}

__global__ __launch_bounds__(256) void scan3_kernel(int* __restrict__ cur, const int* __restrict__ bsum) {
  int i = blockIdx.x * 256 + threadIdx.x;
  cur[i] += bsum[blockIdx.x];
}

__global__ __launch_bounds__(256) void scatter_kernel(
    const void* __restrict__ edges, const int* __restrict__ flag,
    int* __restrict__ cur, int* __restrict__ perm) {
  int is64 = *flag;
  int i = blockIdx.x * 256 + threadIdx.x;
  if (i < Ne) {
    int r = eidx(edges, i, is64);
    int pos = atomicAdd(&cur[r], 1);
    perm[pos] = i;
  }
}

// ---------------- embedding: h = h0 @ w_in + b_in (writes f32 h + bf16 mirror) ----------------
__global__ __launch_bounds__(256) void embed_kernel(
    const float* __restrict__ h0, const float* __restrict__ b_in,
    const unsigned short* __restrict__ frags, float* __restrict__ h,
    unsigned short* __restrict__ hbf) {
  __shared__ __align__(16) unsigned short Xs[64 * 40];
  const int tid = threadIdx.x;
  const int n0 = blockIdx.x * 64;
  for (int f = tid; f < 512; f += 256) {
    int ns = f >> 3, c = (f & 7) * 4;
    int node = n0 + ns; if (node >= Nn) node = Nn - 1;
    st4bf(&Xs[ns * 40 + c], *(const float4*)&h0[(size_t)node * 32 + c]);
  }
  __syncthreads();
  const int lane = tid & 63, w = tid >> 6;
  const int s = lane & 15, q = lane >> 4;
  const int jt0 = 2 * w;
  f32x4 z = {0.f, 0.f, 0.f, 0.f};
  f32x4 acc[2][4];
#pragma unroll
  for (int n = 0; n < 2; ++n)
#pragma unroll
    for (int e = 0; e < 4; ++e) acc[n][e] = z;
  const unsigned short* Af = frags + EMBF;
  bf16x8 a0 = *(const bf16x8*)(Af + ((jt0 + 0) * 64 + lane) * 8);
  bf16x8 a1 = *(const bf16x8*)(Af + ((jt0 + 1) * 64 + lane) * 8);
#pragma unroll
  for (int et = 0; et < 4; ++et) {
    bf16x8 b = *(const bf16x8*)&Xs[(16 * et + s) * 40 + q * 8];
    acc[0][et] = mfma16(a0, b, acc[0][et]);
    acc[1][et] = mfma16(a1, b, acc[1][et]);
  }
#pragma unroll
  for (int n = 0; n < 2; ++n) {
    int j0 = (jt0 + n) * 16 + 4 * q;
    float4 bi = *(const float4*)&b_in[j0];
#pragma unroll
    for (int et = 0; et < 4; ++et) {
      int node = n0 + 16 * et + s;
      if (node < Nn) {
        float4 o;
        o.x = acc[n][et][0] + bi.x; o.y = acc[n][et][1] + bi.y;
        o.z = acc[n][et][2] + bi.z; o.w = acc[n][et][3] + bi.w;
        *(float4*)&h[(size_t)node * 128 + j0] = o;
        st4bf(&hbf[(size_t)node * 128 + j0], o);
      }
    }
  }
}

// ---------------- edge MLP: ONE WAVE = 32 edges, all 128 output channels ----------------
// Small tile -> acc state 64 f32/lane -> VGPR<=128 -> 4 waves/SIMD (16/CU).
// Gathers issued once per edge; interior sorted runs stored, boundary atomic.
__global__ __launch_bounds__(64, 4) void edge_kernel(
    const unsigned short* __restrict__ hbf, const void* __restrict__ edges,
    const float* __restrict__ distances, const float* __restrict__ edge_mask,
    const float* __restrict__ eb1, const float* __restrict__ eb2,
    const unsigned short* __restrict__ w1f, const unsigned short* __restrict__ w2f,
    const float* __restrict__ w1c, float* __restrict__ agg,
    const int* __restrict__ flag, const int* __restrict__ perm) {
  __shared__ __align__(16) unsigned short U[32 * 136];   // 8704 B: T1 then Outb (aliased)
  __shared__ float dist_s[32], em_s[32];
  __shared__ int row_s[32], col_s[32];
  const int tid = threadIdx.x;               // 0..63, one wave
  const int e0 = blockIdx.x * 32;
  const int is64 = *flag;
  if (tid < 32) {
    int eid = perm[e0 + tid];
    row_s[tid]  = eidx(edges, eid, is64);
    col_s[tid]  = eidx(edges, Ne + eid, is64);
    dist_s[tid] = distances[eid];
    em_s[tid]   = edge_mask[eid];
  }
  __syncthreads();
  const int s = tid & 15, q = tid >> 4;
  // per-lane node pointers for the 2 edge sub-tiles
  const unsigned short* bp[2][2];            // [side][et]
#pragma unroll
  for (int et = 0; et < 2; ++et) {
    bp[0][et] = hbf + (size_t)row_s[16 * et + s] * 128 + q * 8;
    bp[1][et] = hbf + (size_t)col_s[16 * et + s] * 128 + q * 8;
  }
  f32x4 z = {0.f, 0.f, 0.f, 0.f};
  f32x4 acc[8][2];
#pragma unroll
  for (int jt = 0; jt < 8; ++jt)
#pragma unroll
    for (int e = 0; e < 2; ++e) acc[jt][e] = z;
  // GEMM1: K=256 ([h_row | h_col]); B gathered once, reused across all 8 jt
#pragma unroll
  for (int kb = 0; kb < 8; ++kb) {
    bf16x8 b[2];
#pragma unroll
    for (int et = 0; et < 2; ++et)
      b[et] = *(const bf16x8*)(bp[kb >> 2][et] + (kb & 3) * 32);
#pragma unroll
    for (int jt = 0; jt < 8; ++jt) {
      bf16x8 a = *(const bf16x8*)(w1f + ((jt * 8 + kb) * 64 + tid) * 8);
#pragma unroll
      for (int et = 0; et < 2; ++et)
        acc[jt][et] = mfma16(a, b[et], acc[jt][et]);
    }
  }
  // epilogue 1: + dist*w1c + b1, relu -> T1 (bf16)
  unsigned short* T1s = U;
  {
    float de[2];
#pragma unroll
    for (int et = 0; et < 2; ++et) de[et] = dist_s[16 * et + s];
#pragma unroll
    for (int jt = 0; jt < 8; ++jt) {
      int j0 = jt * 16 + 4 * q;
      float4 wc = *(const float4*)&w1c[j0];
      float4 bb = *(const float4*)&eb1[j0];
#pragma unroll
      for (int et = 0; et < 2; ++et) {
        float r0 = fmaxf(acc[jt][et][0] + de[et] * wc.x + bb.x, 0.f);
        float r1 = fmaxf(acc[jt][et][1] + de[et] * wc.y + bb.y, 0.f);
        float r2 = fmaxf(acc[jt][et][2] + de[et] * wc.z + bb.z, 0.f);
        float r3 = fmaxf(acc[jt][et][3] + de[et] * wc.w + bb.w, 0.f);
        union { unsigned short u[4]; uint2 d; } t;
        t.u[0] = f2bf(r0); t.u[1] = f2bf(r1); t.u[2] = f2bf(r2); t.u[3] = f2bf(r3);
        *(uint2*)&T1s[(16 * et + s) * 136 + j0] = t.d;
      }
    }
  }
  __syncthreads();
  // GEMM2: K=128
  f32x4 acc2[8][2];
#pragma unroll
  for (int jt = 0; jt < 8; ++jt)
#pragma unroll
    for (int e = 0; e < 2; ++e) acc2[jt][e] = z;
#pragma unroll
  for (int kb = 0; kb < 4; ++kb) {
    bf16x8 b[2];
#pragma unroll
    for (int et = 0; et < 2; ++et)
      b[et] = *(const bf16x8*)&T1s[(16 * et + s) * 136 + kb * 32 + q * 8];
#pragma unroll
    for (int jt = 0; jt < 8; ++jt) {
      bf16x8 a = *(const bf16x8*)(w2f + ((jt * 4 + kb) * 64 + tid) * 8);
#pragma unroll
      for (int et = 0; et < 2; ++et)
        acc2[jt][et] = mfma16(a, b[et], acc2[jt][et]);
    }
  }
  __syncthreads();   // T1 dead; Outb aliases it
  // epilogue 2: + b2, relu, * edge_mask -> Outb (bf16)
  unsigned short* Outb = U;
#pragma unroll
  for (int jt = 0; jt < 8; ++jt) {
    int j0 = jt * 16 + 4 * q;
    float4 bb = *(const float4*)&eb2[j0];
#pragma unroll
    for (int et = 0; et < 2; ++et) {
      int ee = 16 * et + s;
      float em = em_s[ee];
      float4 o;
      o.x = fmaxf(acc2[jt][et][0] + bb.x, 0.f) * em;
      o.y = fmaxf(acc2[jt][et][1] + bb.y, 0.f) * em;
      o.z = fmaxf(acc2[jt][et][2] + bb.z, 0.f) * em;
      o.w = fmaxf(acc2[jt][et][3] + bb.w, 0.f) * em;
      st4bf(&Outb[ee * 136 + j0], o);
    }
  }
  __syncthreads();
  // run-length reduce over sorted rows: lane owns channel pair (2t, 2t+1).
  // Interior rows exclusively owned -> plain store; block-boundary rows atomic.
  const int rowFirst = row_s[0], rowLast = row_s[31];
  float s0 = 0.f, s1 = 0.f;
  int prow = rowFirst;
  for (int es = 0; es < 32; ++es) {
    int r = row_s[es];
    if (r != prow) {
      float* ap = &agg[(size_t)prow * 128 + 2 * tid];
      if (prow == rowFirst || prow == rowLast) {
        atomicAdd(ap + 0, s0); atomicAdd(ap + 1, s1);
      } else {
        *(float2*)ap = make_float2(s0, s1);
      }
      s0 = 0.f; s1 = 0.f; prow = r;
    }
    unsigned pv = *(const unsigned*)&Outb[es * 136 + 2 * tid];
    s0 += bf2f((unsigned short)(pv & 0xffffu));
    s1 += bf2f((unsigned short)(pv >> 16));
  }
  {
    float* ap = &agg[(size_t)prow * 128 + 2 * tid];
    atomicAdd(ap + 0, s0); atomicAdd(ap + 1, s1);   // last run always boundary
  }
}

// ---------------- node MLP: h = (h + MLP([h,agg])) * node_mask ----------------
__global__ __launch_bounds__(256, 8) void node_kernel(
    float* __restrict__ h, unsigned short* __restrict__ hbf,
    const float* __restrict__ agg, const float* __restrict__ node_mask,
    const float* __restrict__ nb1, const float* __restrict__ nb2,
    const unsigned short* __restrict__ w1f, const unsigned short* __restrict__ w2f) {
  __shared__ __align__(16) unsigned short U[64 * 136];   // Ms then T1s (aliased)
  const int tid = threadIdx.x;
  const int n0 = blockIdx.x * 64;
  const int cg = (tid & 31) * 4;
  for (int ns = tid >> 5; ns < 64; ns += 8) {
    int node = n0 + ns; if (node >= Nn) node = Nn - 1;
    st4bf(&U[ns * 136 + cg], *(const float4*)&agg[(size_t)node * 128 + cg]);
  }
  __syncthreads();
  const int lane = tid & 63, w = tid >> 6;
  const int s = lane & 15, q = lane >> 4;
  const int jt0 = 2 * w;
  const unsigned short* bp[4];
#pragma unroll
  for (int et = 0; et < 4; ++et) {
    int node = n0 + 16 * et + s; if (node >= Nn) node = Nn - 1;
    bp[et] = hbf + (size_t)node * 128 + q * 8;
  }
  f32x4 z = {0.f, 0.f, 0.f, 0.f};
  f32x4 acc[2][4];
#pragma unroll
  for (int n = 0; n < 2; ++n)
#pragma unroll
    for (int e = 0; e < 4; ++e) acc[n][e] = z;
#pragma unroll
  for (int kb = 0; kb < 8; ++kb) {
    bf16x8 a0 = *(const bf16x8*)(w1f + (((jt0 + 0) * 8 + kb) * 64 + lane) * 8);
    bf16x8 a1 = *(const bf16x8*)(w1f + (((jt0 + 1) * 8 + kb) * 64 + lane) * 8);
#pragma unroll
    for (int et = 0; et < 4; ++et) {
      bf16x8 b;
      if (kb < 4) b = *(const bf16x8*)(bp[et] + kb * 32);
      else        b = *(const bf16x8*)&U[(16 * et + s) * 136 + (kb & 3) * 32 + q * 8];
      acc[0][et] = mfma16(a0, b, acc[0][et]);
      acc[1][et] = mfma16(a1, b, acc[1][et]);
    }
  }
  __syncthreads();   // Ms dead; T1s aliases it
#pragma unroll
  for (int n = 0; n < 2; ++n) {
    int j0 = (jt0 + n) * 16 + 4 * q;
    float4 bb = *(const float4*)&nb1[j0];
#pragma unroll
    for (int et = 0; et < 4; ++et) {
      float r0 = fmaxf(acc[n][et][0] + bb.x, 0.f);
      float r1 = fmaxf(acc[n][et][1] + bb.y, 0.f);
      float r2 = fmaxf(acc[n][et][2] + bb.z, 0.f);
      float r3 = fmaxf(acc[n][et][3] + bb.w, 0.f);
      union { unsigned short u[4]; uint2 d; } t;
      t.u[0] = f2bf(r0); t.u[1] = f2bf(r1); t.u[2] = f2bf(r2); t.u[3] = f2bf(r3);
      *(uint2*)&U[(16 * et + s) * 136 + j0] = t.d;
    }
  }
  __syncthreads();
  f32x4 acc2[2][4];
#pragma unroll
  for (int n = 0; n < 2; ++n)
#pragma unroll
    for (int e = 0; e < 4; ++e) acc2[n][e] = z;
#pragma unroll
  for (int kb = 0; kb < 4; ++kb) {
    bf16x8 a0 = *(const bf16x8*)(w2f + (((jt0 + 0) * 4 + kb) * 64 + lane) * 8);
    bf16x8 a1 = *(const bf16x8*)(w2f + (((jt0 + 1) * 4 + kb) * 64 + lane) * 8);
#pragma unroll
    for (int et = 0; et < 4; ++et) {
      bf16x8 b = *(const bf16x8*)&U[(16 * et + s) * 136 + kb * 32 + q * 8];
      acc2[0][et] = mfma16(a0, b, acc2[0][et]);
      acc2[1][et] = mfma16(a1, b, acc2[1][et]);
    }
  }
#pragma unroll
  for (int n = 0; n < 2; ++n) {
    int j0 = (jt0 + n) * 16 + 4 * q;
    float4 bb = *(const float4*)&nb2[j0];
#pragma unroll
    for (int et = 0; et < 4; ++et) {
      int node = n0 + 16 * et + s;
      if (node < Nn) {
        float nm = node_mask[node];
        float4 old = *(const float4*)&h[(size_t)node * 128 + j0];
        float4 o;
        o.x = (old.x + acc2[n][et][0] + bb.x) * nm;
        o.y = (old.y + acc2[n][et][1] + bb.y) * nm;
        o.z = (old.z + acc2[n][et][2] + bb.z) * nm;
        o.w = (old.w + acc2[n][et][3] + bb.w) * nm;
        *(float4*)&h[(size_t)node * 128 + j0] = o;
        st4bf(&hbf[(size_t)node * 128 + j0], o);
      }
    }
  }
}

// ---------------- output projection: out = h @ w_out + b_out (direct-global B) ----------------
__global__ __launch_bounds__(256) void out_kernel(
    const unsigned short* __restrict__ hbf, const float* __restrict__ b_out,
    const unsigned short* __restrict__ wf, float* __restrict__ out) {
  const int tid = threadIdx.x;
  const int n0 = blockIdx.x * 64;
  const int lane = tid & 63, w = tid >> 6;
  const int s = lane & 15, q = lane >> 4;
  int node = n0 + 16 * w + s;
  int nc = (node < Nn) ? node : (Nn - 1);
  f32x4 acc = {0.f, 0.f, 0.f, 0.f};
#pragma unroll
  for (int kb = 0; kb < 4; ++kb) {
    bf16x8 a = *(const bf16x8*)(wf + (kb * 64 + lane) * 8);
    bf16x8 b = *(const bf16x8*)(hbf + (size_t)nc * 128 + kb * 32 + q * 8);
    acc = mfma16(a, b, acc);
  }
  if (node < Nn) {
#pragma unroll
    for (int r = 0; r < 4; ++r) {
      int j = 4 * q + r;
      if (j < 10) out[(size_t)node * 10 + j] = acc[r] + b_out[j];
    }
  }
}

extern "C" void kernel_launch(void* const* d_in, const int* in_sizes, int n_in,
                              void* d_out, int out_size, void* d_ws, size_t ws_size,
                              hipStream_t stream) {
  const float* h0        = (const float*)d_in[0];
  const void*  edges     = d_in[1];
  const float* dist      = (const float*)d_in[2];
  const float* node_mask = (const float*)d_in[3];
  const float* edge_mask = (const float*)d_in[4];
  const float* w_in      = (const float*)d_in[5];
  const float* b_in      = (const float*)d_in[6];
  const float* w_out     = (const float*)d_in[7];
  const float* b_out     = (const float*)d_in[8];
  const float* edge_w1   = (const float*)d_in[9];
  const float* edge_b1   = (const float*)d_in[10];
  const float* edge_w2   = (const float*)d_in[11];
  const float* edge_b2   = (const float*)d_in[12];
  const float* node_w1   = (const float*)d_in[13];
  const float* node_b1   = (const float*)d_in[14];
  const float* node_w2   = (const float*)d_in[15];
  const float* node_b2   = (const float*)d_in[16];

  char* ws = (char*)d_ws;
  float* h               = (float*)(ws + H_OFF);
  float* agg             = (float*)(ws + AGG_OFF);
  unsigned short* frags  = (unsigned short*)(ws + FRAG_OFF);
  float* w1c             = (float*)(ws + W1C_OFF);
  int* flag              = (int*)(ws + FLAG_OFF);
  int* cur               = (int*)(ws + CUR_OFF);
  int* bsum              = (int*)(ws + BS_OFF);
  int* perm              = (int*)(ws + PERM_OFF);
  unsigned short* hbf    = (unsigned short*)(ws + HBF_OFF);

  hipMemsetAsync(cur, 0, (NSCAN + 256) * 4, stream);
  prep_kernel<<<793, 256, 0, stream>>>(w_in, w_out, edge_w1, edge_w2,
                                       node_w1, node_w2, edges, frags, w1c, flag);
  hist_kernel<<<(Ne + 255) / 256, 256, 0, stream>>>(edges, flag, cur);
  scan1_kernel<<<NSCAN / 256, 256, 0, stream>>>(cur, bsum);
  scan2_kernel<<<1, 256, 0, stream>>>(bsum);
  scan3_kernel<<<NSCAN / 256, 256, 0, stream>>>(cur, bsum);
  scatter_kernel<<<(Ne + 255) / 256, 256, 0, stream>>>(edges, flag, cur, perm);

  const int nb_n = (Nn + 63) / 64;  // 782
  embed_kernel<<<nb_n, 256, 0, stream>>>(h0, b_in, frags, h, hbf);
  for (int l = 0; l < 2; ++l) {
    hipMemsetAsync(agg, 0, (size_t)Nn * 128 * 4, stream);
    edge_kernel<<<Ne / 32, 64, 0, stream>>>(
        hbf, edges, dist, edge_mask,
        edge_b1 + l * 128, edge_b2 + l * 128,
        frags + (l ? EW1F1 : EW1F0), frags + (l ? EW2F1 : EW2F0),
        w1c + l * 128, agg, flag, perm);
    node_kernel<<<nb_n, 256, 0, stream>>>(
        h, hbf, agg, node_mask,
        node_b1 + l * 128, node_b2 + l * 128,
        frags + (l ? NW1F1 : NW1F0), frags + (l ? NW2F1 : NW2F0));
  }
  out_kernel<<<nb_n, 256, 0, stream>>>(hbf, b_out, frags + WOUTF, (float*)d_out);
}

// Round 8
// 649.704 us; speedup vs baseline: 1.2562x; 1.1982x over previous
//
#include <hip/hip_runtime.h>
#include <stdint.h>

#define Nn 50000
#define Ne 800000
#define TPB_TILES 5                             // 64-edge tiles per block; 2500 blocks

typedef __bf16 bf16x8 __attribute__((ext_vector_type(8)));
typedef float f32x4 __attribute__((ext_vector_type(4)));

// ---- ws layout (bytes) ----
#define H_OFF    0
#define AGG_OFF  (Nn * 128 * 4)                 // 25,600,000
#define FRAG_OFF (2 * Nn * 128 * 4)             // 51,200,000
// fragment segment offsets (bf16 elements, relative to FRAG_OFF)
#define EMBF   0
#define EW1F0  4096
#define EW2F0  36864
#define NW1F0  53248
#define NW2F0  86016
#define EW1F1  102400
#define EW2F1  135168
#define NW1F1  151552
#define NW2F1  184320
#define WOUTF  200704
#define FRAG_ELEMS 202752
#define W1C_OFF  (FRAG_OFF + FRAG_ELEMS * 2)    // 51,605,504
#define FLAG_OFF (W1C_OFF + 2 * 128 * 4)        // 51,606,528
// CSR build scratch
#define NSCAN    50176                          // 196 * 256 >= Nn
#define CUR_OFF  (FLAG_OFF + 16)                // 51,606,544
#define BS_OFF   (CUR_OFF + NSCAN * 4)          // 51,807,248
#define ROWV_OFF (BS_OFF + 256 * 4)             // 51,808,272  (Ne*4)
#define HBF_OFF  (ROWV_OFF + Ne * 4)            // 55,008,272  (Nn*128*2 = 12.8MB)
#define COLV_OFF (HBF_OFF + Nn * 128 * 2)       // 67,808,272  (Ne*4)
#define DMV_OFF  (COLV_OFF + Ne * 4)            // 71,008,272  (Ne*8) -> end 77.4MB

static __device__ __forceinline__ unsigned short f2bf(float f) {
  union { float f; unsigned u; } v; v.f = f;
  unsigned r = v.u + 0x7fffu + ((v.u >> 16) & 1u);   // RNE
  return (unsigned short)(r >> 16);
}

static __device__ __forceinline__ float bf2f(unsigned short u) {
  union { unsigned u; float f; } t; t.u = ((unsigned)u) << 16; return t.f;
}

static __device__ __forceinline__ void st4bf(unsigned short* p, float4 v) {
  union { unsigned short u[4]; uint2 d; } t;
  t.u[0] = f2bf(v.x); t.u[1] = f2bf(v.y); t.u[2] = f2bf(v.z); t.u[3] = f2bf(v.w);
  *(uint2*)p = t.d;
}

static __device__ __forceinline__ f32x4 mfma16(bf16x8 a, bf16x8 b, f32x4 c) {
  return __builtin_amdgcn_mfma_f32_16x16x32_bf16(a, b, c, 0, 0, 0);
}

static __device__ __forceinline__ int eidx(const void* edges, int i, int is64) {
  if (is64) return (int)((const long long*)edges)[i];
  return ((const int*)edges)[i];
}

// ---------------- weight prep: f32 -> bf16 fragment-linear ----------------
__global__ __launch_bounds__(256) void prep_kernel(
    const float* __restrict__ w_in, const float* __restrict__ w_out,
    const float* __restrict__ edge_w1, const float* __restrict__ edge_w2,
    const float* __restrict__ node_w1, const float* __restrict__ node_w2,
    const void* __restrict__ edges,
    unsigned short* __restrict__ frags, float* __restrict__ w1c, int* __restrict__ flag) {
  int gid = blockIdx.x * 256 + threadIdx.x;
  if (gid == 0) {
    const unsigned* e32 = (const unsigned*)edges;
    int allz = 1;
    for (int i = 0; i < 64; ++i) if (e32[2 * i + 1] != 0u) { allz = 0; break; }
    *flag = allz;
  }
  if (gid < FRAG_ELEMS) {
    int base, KB, J10 = 0; const float* src;
    if      (gid < EW1F0) { base = EMBF;  KB = 1; src = w_in; }
    else if (gid < EW2F0) { base = EW1F0; KB = 8; src = edge_w1; }
    else if (gid < NW1F0) { base = EW2F0; KB = 4; src = edge_w2; }
    else if (gid < NW2F0) { base = NW1F0; KB = 8; src = node_w1; }
    else if (gid < EW1F1) { base = NW2F0; KB = 4; src = node_w2; }
    else if (gid < EW2F1) { base = EW1F1; KB = 8; src = edge_w1 + 257 * 128; }
    else if (gid < NW1F1) { base = EW2F1; KB = 4; src = edge_w2 + 128 * 128; }
    else if (gid < NW2F1) { base = NW1F1; KB = 8; src = node_w1 + 256 * 128; }
    else if (gid < WOUTF) { base = NW2F1; KB = 4; src = node_w2 + 128 * 128; }
    else                  { base = WOUTF; KB = 4; src = w_out; J10 = 1; }
    int f = gid - base;
    int i = f & 7, lane = (f >> 3) & 63;
    int rest = f >> 9;
    int kb = rest % KB, jt = rest / KB;
    int j = jt * 16 + (lane & 15);
    int k = kb * 32 + (lane >> 4) * 8 + i;
    float v;
    if (J10) v = (j < 10) ? src[k * 10 + j] : 0.f;
    else     v = src[k * 128 + j];
    frags[gid] = f2bf(v);
  } else if (gid < FRAG_ELEMS + 256) {
    int idx = gid - FRAG_ELEMS;
    int l = idx >> 7, j = idx & 127;
    w1c[idx] = edge_w1[l * (257 * 128) + 256 * 128 + j];
  }
}

// ---------------- CSR build: hist -> scan -> scatter (sorted id arrays) ----------------
__global__ __launch_bounds__(256) void hist_kernel(
    const void* __restrict__ edges, const int* __restrict__ flag, int* __restrict__ cur) {
  int is64 = *flag;
  int i = blockIdx.x * 256 + threadIdx.x;
  if (i < Ne) atomicAdd(&cur[eidx(edges, i, is64)], 1);
}

__global__ __launch_bounds__(256) void scan1_kernel(int* __restrict__ cur, int* __restrict__ bsum) {
  __shared__ int s[256];
  int tid = threadIdx.x;
  int i = blockIdx.x * 256 + tid;
  s[tid] = cur[i];
  __syncthreads();
#pragma unroll
  for (int off = 1; off < 256; off <<= 1) {
    int t = (tid >= off) ? s[tid - off] : 0;
    __syncthreads();
    s[tid] += t;
    __syncthreads();
  }
  cur[i] = tid ? s[tid - 1] : 0;
  if (tid == 255) bsum[blockIdx.x] = s[255];
}

__global__ __launch_bounds__(256) void scan2_kernel(int* __restrict__ bsum) {
  __shared__ int s[256];
  int tid = threadIdx.x;
  s[tid] = bsum[tid];
  __syncthreads();
#pragma unroll
  for (int off = 1; off < 256; off <<= 1) {
    int t = (tid >= off) ? s[tid - off] : 0;
    __syncthreads();
    s[tid] += t;
    __syncthreads();
  }
  bsum[tid] = tid ? s[tid - 1] : 0;
}

__global__ __launch_bounds__(256) void scan3_kernel(int* __restrict__ cur, const int* __restrict__ bsum) {
  int i = blockIdx.x * 256 + threadIdx.x;
  cur[i] += bsum[blockIdx.x];
}

__global__ __launch_bounds__(256) void scatter_kernel(
    const void* __restrict__ edges, const int* __restrict__ flag,
    const float* __restrict__ distances, const float* __restrict__ edge_mask,
    int* __restrict__ cur, int* __restrict__ rowv, int* __restrict__ colv,
    float2* __restrict__ dmv) {
  int is64 = *flag;
  int i = blockIdx.x * 256 + threadIdx.x;
  if (i < Ne) {
    int r = eidx(edges, i, is64);
    int c = eidx(edges, Ne + i, is64);
    int pos = atomicAdd(&cur[r], 1);
    rowv[pos] = r;
    colv[pos] = c;
    dmv[pos] = make_float2(distances[i], edge_mask[i]);
  }
}

// ---------------- embedding: h = h0 @ w_in + b_in (writes f32 h + bf16 mirror) ----------------
__global__ __launch_bounds__(256) void embed_kernel(
    const float* __restrict__ h0, const float* __restrict__ b_in,
    const unsigned short* __restrict__ frags, float* __restrict__ h,
    unsigned short* __restrict__ hbf) {
  __shared__ __align__(16) unsigned short Xs[64 * 40];
  const int tid = threadIdx.x;
  const int n0 = blockIdx.x * 64;
  for (int f = tid; f < 512; f += 256) {
    int ns = f >> 3, c = (f & 7) * 4;
    int node = n0 + ns; if (node >= Nn) node = Nn - 1;
    st4bf(&Xs[ns * 40 + c], *(const float4*)&h0[(size_t)node * 32 + c]);
  }
  __syncthreads();
  const int lane = tid & 63, w = tid >> 6;
  const int s = lane & 15, q = lane >> 4;
  const int jt0 = 2 * w;
  f32x4 z = {0.f, 0.f, 0.f, 0.f};
  f32x4 acc[2][4];
#pragma unroll
  for (int n = 0; n < 2; ++n)
#pragma unroll
    for (int e = 0; e < 4; ++e) acc[n][e] = z;
  const unsigned short* Af = frags + EMBF;
  bf16x8 a0 = *(const bf16x8*)(Af + ((jt0 + 0) * 64 + lane) * 8);
  bf16x8 a1 = *(const bf16x8*)(Af + ((jt0 + 1) * 64 + lane) * 8);
#pragma unroll
  for (int et = 0; et < 4; ++et) {
    bf16x8 b = *(const bf16x8*)&Xs[(16 * et + s) * 40 + q * 8];
    acc[0][et] = mfma16(a0, b, acc[0][et]);
    acc[1][et] = mfma16(a1, b, acc[1][et]);
  }
#pragma unroll
  for (int n = 0; n < 2; ++n) {
    int j0 = (jt0 + n) * 16 + 4 * q;
    float4 bi = *(const float4*)&b_in[j0];
#pragma unroll
    for (int et = 0; et < 4; ++et) {
      int node = n0 + 16 * et + s;
      if (node < Nn) {
        float4 o;
        o.x = acc[n][et][0] + bi.x; o.y = acc[n][et][1] + bi.y;
        o.z = acc[n][et][2] + bi.z; o.w = acc[n][et][3] + bi.w;
        *(float4*)&h[(size_t)node * 128 + j0] = o;
        st4bf(&hbf[(size_t)node * 128 + j0], o);
      }
    }
  }
}

// ---------------- edge MLP: weights in registers, 5x64-edge tiles per block ----------------
// 4 waves; wave w owns jt {2w, 2w+1}. X staged once per tile into LDS with
// XOR-swizzled chunks (c16 ^ (e&7)) for conflict-free ds_read_b128.
__global__ __launch_bounds__(256, 2) void edge_kernel(
    const unsigned short* __restrict__ hbf,
    const int* __restrict__ rowv, const int* __restrict__ colv,
    const float2* __restrict__ dmv,
    const float* __restrict__ eb1, const float* __restrict__ eb2,
    const unsigned short* __restrict__ w1f, const unsigned short* __restrict__ w2f,
    const float* __restrict__ w1c, float* __restrict__ agg) {
  __shared__ __align__(16) unsigned short Xs[64 * 256];   // 32KB: [e][c16^(e&7)] 16B chunks
  __shared__ __align__(16) unsigned short T1[64 * 136];   // 17.4KB: T1 then Outb (aliased)
  const int tid = threadIdx.x;
  const int l = tid & 63, w = tid >> 6;
  const int s = l & 15, q = l >> 4;
  const int base = blockIdx.x * (TPB_TILES * 64);
  // persistent weight fragments (96 VGPR)
  bf16x8 wA1[2][8], wA2[2][4];
#pragma unroll
  for (int n = 0; n < 2; ++n) {
#pragma unroll
    for (int kb = 0; kb < 8; ++kb)
      wA1[n][kb] = *(const bf16x8*)(w1f + (((2 * w + n) * 8 + kb) * 64 + l) * 8);
#pragma unroll
    for (int kb = 0; kb < 4; ++kb)
      wA2[n][kb] = *(const bf16x8*)(w2f + (((2 * w + n) * 4 + kb) * 64 + l) * 8);
  }
  float4 wcr[2], b1r[2], b2r[2];
#pragma unroll
  for (int n = 0; n < 2; ++n) {
    int j0 = (2 * w + n) * 16 + 4 * q;
    wcr[n] = *(const float4*)&w1c[j0];
    b1r[n] = *(const float4*)&eb1[j0];
    b2r[n] = *(const float4*)&eb2[j0];
  }
  // ids for tile 0 (each wave holds all 64, for shfl)
  int rv = rowv[base + l];
  int cv = colv[base + l];
  float2 dm = dmv[base + l];
  f32x4 z = {0.f, 0.f, 0.f, 0.f};

  for (int t = 0; t < TPB_TILES; ++t) {
    // ---- stage X: wave w loads edges 16w..16w+15 (8 x 1KB chunks), swizzled src ----
    uint4 st[8];
#pragma unroll
    for (int k = 0; k < 8; ++k) {
      int i = w * 8 + k;
      int e = 2 * i + (l >> 5);          // edge 0..63
      int p16 = l & 31;                  // physical 16B slot
      int c16 = p16 ^ (e & 7);           // logical chunk (involution)
      int node = (c16 & 16) ? __shfl(cv, e) : __shfl(rv, e);
      st[k] = *(const uint4*)(hbf + (size_t)node * 128 + (c16 & 15) * 8);
    }
    // prefetch next tile's ids (overlaps with this tile's compute)
    int tn = (t + 1 < TPB_TILES) ? (t + 1) : t;
    int rvn = rowv[base + tn * 64 + l];
    int cvn = colv[base + tn * 64 + l];
    float2 dmn = dmv[base + tn * 64 + l];
    // linear LDS write (swizzle already applied on source side)
#pragma unroll
    for (int k = 0; k < 8; ++k) {
      int i = w * 8 + k;
      *(uint4*)&Xs[i * 512 + l * 8] = st[k];
    }
    __syncthreads();   // B1: X ready; also orders prev-tile reduce before T1 writes
    // ---- GEMM1: K=256, B from swizzled Xs, A from registers ----
    f32x4 acc[2][4];
#pragma unroll
    for (int n = 0; n < 2; ++n)
#pragma unroll
      for (int e = 0; e < 4; ++e) acc[n][e] = z;
#pragma unroll
    for (int kb = 0; kb < 8; ++kb) {
      bf16x8 b[4];
#pragma unroll
      for (int et = 0; et < 4; ++et) {
        int e = 16 * et + s;
        int c16 = ((kb >> 2) << 4) | ((kb & 3) << 2) | q;
        b[et] = *(const bf16x8*)&Xs[e * 256 + ((c16 ^ (e & 7)) << 3)];
      }
#pragma unroll
      for (int n = 0; n < 2; ++n)
#pragma unroll
        for (int et = 0; et < 4; ++et)
          acc[n][et] = mfma16(wA1[n][kb], b[et], acc[n][et]);
    }
    // epilogue 1: + dist*w1c + b1, relu -> T1 (bf16)
#pragma unroll
    for (int n = 0; n < 2; ++n) {
      int j0 = (2 * w + n) * 16 + 4 * q;
#pragma unroll
      for (int et = 0; et < 4; ++et) {
        int ee = 16 * et + s;
        float de = __shfl(dm.x, ee);
        float4 o;
        o.x = fmaxf(acc[n][et][0] + de * wcr[n].x + b1r[n].x, 0.f);
        o.y = fmaxf(acc[n][et][1] + de * wcr[n].y + b1r[n].y, 0.f);
        o.z = fmaxf(acc[n][et][2] + de * wcr[n].z + b1r[n].z, 0.f);
        o.w = fmaxf(acc[n][et][3] + de * wcr[n].w + b1r[n].w, 0.f);
        st4bf(&T1[ee * 136 + j0], o);
      }
    }
    __syncthreads();   // B2: T1 ready
    // ---- GEMM2: K=128 ----
    f32x4 acc2[2][4];
#pragma unroll
    for (int n = 0; n < 2; ++n)
#pragma unroll
      for (int e = 0; e < 4; ++e) acc2[n][e] = z;
#pragma unroll
    for (int kb = 0; kb < 4; ++kb) {
      bf16x8 b[4];
#pragma unroll
      for (int et = 0; et < 4; ++et)
        b[et] = *(const bf16x8*)&T1[(16 * et + s) * 136 + kb * 32 + q * 8];
#pragma unroll
      for (int n = 0; n < 2; ++n)
#pragma unroll
        for (int et = 0; et < 4; ++et)
          acc2[n][et] = mfma16(wA2[n][kb], b[et], acc2[n][et]);
    }
    __syncthreads();   // B3: all T1 reads done; Outb aliases T1
    // epilogue 2: + b2, relu, * edge_mask -> Outb (bf16)
#pragma unroll
    for (int n = 0; n < 2; ++n) {
      int j0 = (2 * w + n) * 16 + 4 * q;
#pragma unroll
      for (int et = 0; et < 4; ++et) {
        int ee = 16 * et + s;
        float em = __shfl(dm.y, ee);
        float4 o;
        o.x = fmaxf(acc2[n][et][0] + b2r[n].x, 0.f) * em;
        o.y = fmaxf(acc2[n][et][1] + b2r[n].y, 0.f) * em;
        o.z = fmaxf(acc2[n][et][2] + b2r[n].z, 0.f) * em;
        o.w = fmaxf(acc2[n][et][3] + b2r[n].w, 0.f) * em;
        st4bf(&T1[ee * 136 + j0], o);
      }
    }
    __syncthreads();   // B4: Outb ready
    // ---- run-length reduce: thread (half, c) sums 32 edges of channel c ----
    {
      const int c = tid & 127, es0 = (tid >> 7) * 32;
      int rfirst = __shfl(rv, es0), rlast = __shfl(rv, es0 + 31);
      float sum = 0.f;
      int prow = rfirst;
      for (int es = es0; es < es0 + 32; ++es) {
        int r = __shfl(rv, es);
        if (r != prow) {
          float* ap = &agg[(size_t)prow * 128 + c];
          if (prow == rfirst || prow == rlast) atomicAdd(ap, sum);
          else *ap = sum;              // interior run: exclusive ownership
          sum = 0.f; prow = r;
        }
        sum += bf2f(T1[es * 136 + c]);
      }
      atomicAdd(&agg[(size_t)prow * 128 + c], sum);   // last run: boundary
    }
    rv = rvn; cv = cvn; dm = dmn;
    // next iteration's B1 orders this reduce's Outb reads before T1 overwrite
  }
}

// ---------------- node MLP: h = (h + MLP([h,agg])) * node_mask ----------------
__global__ __launch_bounds__(256, 8) void node_kernel(
    float* __restrict__ h, unsigned short* __restrict__ hbf,
    const float* __restrict__ agg, const float* __restrict__ node_mask,
    const float* __restrict__ nb1, const float* __restrict__ nb2,
    const unsigned short* __restrict__ w1f, const unsigned short* __restrict__ w2f) {
  __shared__ __align__(16) unsigned short U[64 * 136];   // Ms then T1s (aliased)
  const int tid = threadIdx.x;
  const int n0 = blockIdx.x * 64;
  const int cg = (tid & 31) * 4;
  for (int ns = tid >> 5; ns < 64; ns += 8) {
    int node = n0 + ns; if (node >= Nn) node = Nn - 1;
    st4bf(&U[ns * 136 + cg], *(const float4*)&agg[(size_t)node * 128 + cg]);
  }
  __syncthreads();
  const int lane = tid & 63, w = tid >> 6;
  const int s = lane & 15, q = lane >> 4;
  const int jt0 = 2 * w;
  const unsigned short* bp[4];
#pragma unroll
  for (int et = 0; et < 4; ++et) {
    int node = n0 + 16 * et + s; if (node >= Nn) node = Nn - 1;
    bp[et] = hbf + (size_t)node * 128 + q * 8;
  }
  f32x4 z = {0.f, 0.f, 0.f, 0.f};
  f32x4 acc[2][4];
#pragma unroll
  for (int n = 0; n < 2; ++n)
#pragma unroll
    for (int e = 0; e < 4; ++e) acc[n][e] = z;
#pragma unroll
  for (int kb = 0; kb < 8; ++kb) {
    bf16x8 a0 = *(const bf16x8*)(w1f + (((jt0 + 0) * 8 + kb) * 64 + lane) * 8);
    bf16x8 a1 = *(const bf16x8*)(w1f + (((jt0 + 1) * 8 + kb) * 64 + lane) * 8);
#pragma unroll
    for (int et = 0; et < 4; ++et) {
      bf16x8 b;
      if (kb < 4) b = *(const bf16x8*)(bp[et] + kb * 32);
      else        b = *(const bf16x8*)&U[(16 * et + s) * 136 + (kb & 3) * 32 + q * 8];
      acc[0][et] = mfma16(a0, b, acc[0][et]);
      acc[1][et] = mfma16(a1, b, acc[1][et]);
    }
  }
  __syncthreads();   // Ms dead; T1s aliases it
#pragma unroll
  for (int n = 0; n < 2; ++n) {
    int j0 = (jt0 + n) * 16 + 4 * q;
    float4 bb = *(const float4*)&nb1[j0];
#pragma unroll
    for (int et = 0; et < 4; ++et) {
      float r0 = fmaxf(acc[n][et][0] + bb.x, 0.f);
      float r1 = fmaxf(acc[n][et][1] + bb.y, 0.f);
      float r2 = fmaxf(acc[n][et][2] + bb.z, 0.f);
      float r3 = fmaxf(acc[n][et][3] + bb.w, 0.f);
      union { unsigned short u[4]; uint2 d; } t;
      t.u[0] = f2bf(r0); t.u[1] = f2bf(r1); t.u[2] = f2bf(r2); t.u[3] = f2bf(r3);
      *(uint2*)&U[(16 * et + s) * 136 + j0] = t.d;
    }
  }
  __syncthreads();
  f32x4 acc2[2][4];
#pragma unroll
  for (int n = 0; n < 2; ++n)
#pragma unroll
    for (int e = 0; e < 4; ++e) acc2[n][e] = z;
#pragma unroll
  for (int kb = 0; kb < 4; ++kb) {
    bf16x8 a0 = *(const bf16x8*)(w2f + (((jt0 + 0) * 4 + kb) * 64 + lane) * 8);
    bf16x8 a1 = *(const bf16x8*)(w2f + (((jt0 + 1) * 4 + kb) * 64 + lane) * 8);
#pragma unroll
    for (int et = 0; et < 4; ++et) {
      bf16x8 b = *(const bf16x8*)&U[(16 * et + s) * 136 + kb * 32 + q * 8];
      acc2[0][et] = mfma16(a0, b, acc2[0][et]);
      acc2[1][et] = mfma16(a1, b, acc2[1][et]);
    }
  }
#pragma unroll
  for (int n = 0; n < 2; ++n) {
    int j0 = (jt0 + n) * 16 + 4 * q;
    float4 bb = *(const float4*)&nb2[j0];
#pragma unroll
    for (int et = 0; et < 4; ++et) {
      int node = n0 + 16 * et + s;
      if (node < Nn) {
        float nm = node_mask[node];
        float4 old = *(const float4*)&h[(size_t)node * 128 + j0];
        float4 o;
        o.x = (old.x + acc2[n][et][0] + bb.x) * nm;
        o.y = (old.y + acc2[n][et][1] + bb.y) * nm;
        o.z = (old.z + acc2[n][et][2] + bb.z) * nm;
        o.w = (old.w + acc2[n][et][3] + bb.w) * nm;
        *(float4*)&h[(size_t)node * 128 + j0] = o;
        st4bf(&hbf[(size_t)node * 128 + j0], o);
      }
    }
  }
}

// ---------------- output projection: out = h @ w_out + b_out (direct-global B) ----------------
__global__ __launch_bounds__(256) void out_kernel(
    const unsigned short* __restrict__ hbf, const float* __restrict__ b_out,
    const unsigned short* __restrict__ wf, float* __restrict__ out) {
  const int tid = threadIdx.x;
  const int n0 = blockIdx.x * 64;
  const int lane = tid & 63, w = tid >> 6;
  const int s = lane & 15, q = lane >> 4;
  int node = n0 + 16 * w + s;
  int nc = (node < Nn) ? node : (Nn - 1);
  f32x4 acc = {0.f, 0.f, 0.f, 0.f};
#pragma unroll
  for (int kb = 0; kb < 4; ++kb) {
    bf16x8 a = *(const bf16x8*)(wf + (kb * 64 + lane) * 8);
    bf16x8 b = *(const bf16x8*)(hbf + (size_t)nc * 128 + kb * 32 + q * 8);
    acc = mfma16(a, b, acc);
  }
  if (node < Nn) {
#pragma unroll
    for (int r = 0; r < 4; ++r) {
      int j = 4 * q + r;
      if (j < 10) out[(size_t)node * 10 + j] = acc[r] + b_out[j];
    }
  }
}

extern "C" void kernel_launch(void* const* d_in, const int* in_sizes, int n_in,
                              void* d_out, int out_size, void* d_ws, size_t ws_size,
                              hipStream_t stream) {
  const float* h0        = (const float*)d_in[0];
  const void*  edges     = d_in[1];
  const float* dist      = (const float*)d_in[2];
  const float* node_mask = (const float*)d_in[3];
  const float* edge_mask = (const float*)d_in[4];
  const float* w_in      = (const float*)d_in[5];
  const float* b_in      = (const float*)d_in[6];
  const float* w_out     = (const float*)d_in[7];
  const float* b_out     = (const float*)d_in[8];
  const float* edge_w1   = (const float*)d_in[9];
  const float* edge_b1   = (const float*)d_in[10];
  const float* edge_w2   = (const float*)d_in[11];
  const float* edge_b2   = (const float*)d_in[12];
  const float* node_w1   = (const float*)d_in[13];
  const float* node_b1   = (const float*)d_in[14];
  const float* node_w2   = (const float*)d_in[15];
  const float* node_b2   = (const float*)d_in[16];

  char* ws = (char*)d_ws;
  float* h               = (float*)(ws + H_OFF);
  float* agg             = (float*)(ws + AGG_OFF);
  unsigned short* frags  = (unsigned short*)(ws + FRAG_OFF);
  float* w1c             = (float*)(ws + W1C_OFF);
  int* flag              = (int*)(ws + FLAG_OFF);
  int* cur               = (int*)(ws + CUR_OFF);
  int* bsum              = (int*)(ws + BS_OFF);
  int* rowv              = (int*)(ws + ROWV_OFF);
  unsigned short* hbf    = (unsigned short*)(ws + HBF_OFF);
  int* colv              = (int*)(ws + COLV_OFF);
  float2* dmv            = (float2*)(ws + DMV_OFF);

  hipMemsetAsync(cur, 0, (NSCAN + 256) * 4, stream);
  prep_kernel<<<793, 256, 0, stream>>>(w_in, w_out, edge_w1, edge_w2,
                                       node_w1, node_w2, edges, frags, w1c, flag);
  hist_kernel<<<(Ne + 255) / 256, 256, 0, stream>>>(edges, flag, cur);
  scan1_kernel<<<NSCAN / 256, 256, 0, stream>>>(cur, bsum);
  scan2_kernel<<<1, 256, 0, stream>>>(bsum);
  scan3_kernel<<<NSCAN / 256, 256, 0, stream>>>(cur, bsum);
  scatter_kernel<<<(Ne + 255) / 256, 256, 0, stream>>>(edges, flag, dist, edge_mask,
                                                       cur, rowv, colv, dmv);

  const int nb_n = (Nn + 63) / 64;  // 782
  embed_kernel<<<nb_n, 256, 0, stream>>>(h0, b_in, frags, h, hbf);
  for (int l = 0; l < 2; ++l) {
    hipMemsetAsync(agg, 0, (size_t)Nn * 128 * 4, stream);
    edge_kernel<<<Ne / (TPB_TILES * 64), 256, 0, stream>>>(
        hbf, rowv, colv, dmv,
        edge_b1 + l * 128, edge_b2 + l * 128,
        frags + (l ? EW1F1 : EW1F0), frags + (l ? EW2F1 : EW2F0),
        w1c + l * 128, agg);
    node_kernel<<<nb_n, 256, 0, stream>>>(
        h, hbf, agg, node_mask,
        node_b1 + l * 128, node_b2 + l * 128,
        frags + (l ? NW1F1 : NW1F0), frags + (l ? NW2F1 : NW2F0));
  }
  out_kernel<<<nb_n, 256, 0, stream>>>(hbf, b_out, frags + WOUTF, (float*)d_out);
}